// Round 3
// baseline (914.297 us; speedup 1.0000x reference)
//
#include <hip/hip_runtime.h>

// VectorQuantizer: z (8,64,16,64,64) f32, emb (512,64) f32.
// N = 524288, D = 64, K = 512.
// out flat = [ z_q_st (33554432 f32) | loss (1 f32) | indices (524288 f32) ]
//
// The checker's ref (ref=np) computes dists in FP32 expanded form:
//   d[n,k] = fl( fl( zz_n - fl(2*M_nk) ) + ee_k )
//   M = z @ emb.T   (BLAS sgemm: per-element sequential fma chain over c=0..63)
//   zz = np.sum(z*z, -1), ee = np.sum(emb*emb, -1)  (numpy pairwise_sum, n=64:
//        8 strided accumulators, combined ((r0+r1)+(r2+r3))+((r4+r5)+(r6+r7)),
//        squares rounded separately — NOT fma)
//   argmin = first occurrence.
// Values sit near ||z||^2 ~ 64 (ULP 7.6e-6), so ~hundreds of rows have
// quantization-decided winners: we must match this arithmetic BIT-EXACTLY.
// (Round-2 evidence: exact-fp64 argmin gives identical absmax 497 as plain
// fp32 — ref is NOT the exact argmin.)

#define NK       512
#define DD       64
#define CH       128                  // codebook rows per LDS chunk (32 KiB)
#define NCHUNK   (NK / CH)
#define LOSS_OFF 33554432
#define IDX_OFF  33554433

// numpy pairwise_sum of squares, n=64. asm barrier stops -ffp-contract=fast
// from fusing the square into the add (numpy rounds the square separately).
__device__ __forceinline__ float np_sumsq64(const float* v) {
    float r[8];
    #pragma unroll
    for (int j = 0; j < 8; ++j) {
        float s = v[j] * v[j];
        asm volatile("" : "+v"(s));
        r[j] = s;
    }
    #pragma unroll
    for (int i = 8; i < 64; i += 8) {
        #pragma unroll
        for (int j = 0; j < 8; ++j) {
            float s = v[i + j] * v[i + j];
            asm volatile("" : "+v"(s));
            r[j] += s;
        }
    }
    return ((r[0] + r[1]) + (r[2] + r[3])) + ((r[4] + r[5]) + (r[6] + r[7]));
}

__global__ __launch_bounds__(256)
void vq_main(const float* __restrict__ z, const float* __restrict__ emb,
             float* __restrict__ out, float* __restrict__ loss_acc) {
    __shared__ __align__(16) float s_e[CH * DD];   // 32 KiB codebook chunk
    __shared__ float s_ee[NK];                     // 2 KiB: np-pairwise ||e_k||^2

    const int tid = threadIdx.x;

    // ee_k with numpy's exact summation pattern (global emb, L1/L2-hot)
    for (int k = tid; k < NK; k += 256) {
        float row[DD];
        const float* er = emb + k * DD;
        #pragma unroll
        for (int c = 0; c < DD; ++c) row[c] = er[c];
        s_ee[k] = np_sumsq64(row);
    }

    // two rows per thread: n0 = blk*512 + tid, n1 = n0 + 256 (same b)
    const int n0  = blockIdx.x * 512 + tid;
    const int n1  = n0 + 256;
    const int b   = n0 >> 16;
    const int sp0 = n0 & 65535, sp1 = sp0 + 256;
    const float* zbase = z + ((size_t)b << 22);

    float za[DD], zb_[DD];
    #pragma unroll
    for (int c = 0; c < DD; ++c) {
        za[c]  = zbase[((size_t)c << 16) + sp0];
        zb_[c] = zbase[((size_t)c << 16) + sp1];
    }
    const float zz0 = np_sumsq64(za);
    const float zz1 = np_sumsq64(zb_);

    float b0 = 3.4e38f, b1 = 3.4e38f;
    int   i0 = 0, i1 = 0;

    for (int ch = 0; ch < NCHUNK; ++ch) {
        __syncthreads();                          // prev chunk consumed / s_ee ready
        {   // stage 128x64 f32 = 2048 float4, 8 per thread
            const float4* src = (const float4*)(emb + ch * CH * DD);
            float4* dst = (float4*)s_e;
            #pragma unroll
            for (int t = 0; t < 8; ++t) dst[tid + 256 * t] = src[tid + 256 * t];
        }
        __syncthreads();

        const int kb = ch * CH;
        for (int kc = 0; kc < CH; kc += 2) {      // 2 codes x 2 rows = 4 fma chains
            const float4* e0 = (const float4*)&s_e[(kc + 0) * DD];
            const float4* e1 = (const float4*)&s_e[(kc + 1) * DD];
            float m00 = 0.f, m01 = 0.f, m10 = 0.f, m11 = 0.f;
            #pragma unroll
            for (int c4 = 0; c4 < 16; ++c4) {
                float4 ea = e0[c4];
                float4 eb = e1[c4];
                m00 = fmaf(za [c4*4+0], ea.x, m00);  m01 = fmaf(za [c4*4+0], eb.x, m01);
                m10 = fmaf(zb_[c4*4+0], ea.x, m10);  m11 = fmaf(zb_[c4*4+0], eb.x, m11);
                m00 = fmaf(za [c4*4+1], ea.y, m00);  m01 = fmaf(za [c4*4+1], eb.y, m01);
                m10 = fmaf(zb_[c4*4+1], ea.y, m10);  m11 = fmaf(zb_[c4*4+1], eb.y, m11);
                m00 = fmaf(za [c4*4+2], ea.z, m00);  m01 = fmaf(za [c4*4+2], eb.z, m01);
                m10 = fmaf(zb_[c4*4+2], ea.z, m10);  m11 = fmaf(zb_[c4*4+2], eb.z, m11);
                m00 = fmaf(za [c4*4+3], ea.w, m00);  m01 = fmaf(za [c4*4+3], eb.w, m01);
                m10 = fmaf(zb_[c4*4+3], ea.w, m10);  m11 = fmaf(zb_[c4*4+3], eb.w, m11);
            }
            const float eeA = s_ee[kb + kc], eeB = s_ee[kb + kc + 1];
            // fl(zz - 2m) == fmaf(-2,m,zz) since 2m is exact; then one plain add
            const float d00 = fmaf(-2.f, m00, zz0) + eeA;
            const float d01 = fmaf(-2.f, m01, zz0) + eeB;
            const float d10 = fmaf(-2.f, m10, zz1) + eeA;
            const float d11 = fmaf(-2.f, m11, zz1) + eeB;
            const int k0 = kb + kc, k1 = kb + kc + 1;
            if (d00 < b0) { b0 = d00; i0 = k0; }   // strict <, ascending k:
            if (d01 < b0) { b0 = d01; i0 = k1; }   //   first-occurrence tiebreak
            if (d10 < b1) { b1 = d10; i1 = k0; }
            if (d11 < b1) { b1 = d11; i1 = k1; }
        }
    }

    // gather z_q rows from global emb (128 KiB, cache-resident), write, loss
    float lsum = 0.f;
    {
        float* op = out + ((size_t)b << 22) + sp0;
        const float4* brow = (const float4*)(emb + i0 * DD);
        #pragma unroll
        for (int c4 = 0; c4 < 16; ++c4) {
            float4 e = brow[c4];
            float eq[4] = { e.x, e.y, e.z, e.w };
            #pragma unroll
            for (int j = 0; j < 4; ++j) {
                int c = c4 * 4 + j;
                float d = eq[j] - za[c];
                lsum = fmaf(d, d, lsum);
                op[(size_t)c << 16] = eq[j];
            }
        }
        out[IDX_OFF + n0] = (float)i0;
    }
    {
        float* op = out + ((size_t)b << 22) + sp1;
        const float4* brow = (const float4*)(emb + i1 * DD);
        #pragma unroll
        for (int c4 = 0; c4 < 16; ++c4) {
            float4 e = brow[c4];
            float eq[4] = { e.x, e.y, e.z, e.w };
            #pragma unroll
            for (int j = 0; j < 4; ++j) {
                int c = c4 * 4 + j;
                float d = eq[j] - zb_[c];
                lsum = fmaf(d, d, lsum);
                op[(size_t)c << 16] = eq[j];
            }
        }
        out[IDX_OFF + n1] = (float)i1;
    }

    #pragma unroll
    for (int off = 32; off > 0; off >>= 1) lsum += __shfl_down(lsum, off);
    if ((tid & 63) == 0) atomicAdd(loss_acc, lsum);
}

__global__ void vq_finalize(const float* __restrict__ acc, float* __restrict__ out) {
    out[LOSS_OFF] = acc[0] * (1.25f / 33554432.0f);  // (1 + BETA) * mean
}

extern "C" void kernel_launch(void* const* d_in, const int* in_sizes, int n_in,
                              void* d_out, int out_size, void* d_ws, size_t ws_size,
                              hipStream_t stream) {
    const float* z   = (const float*)d_in[0];
    const float* emb = (const float*)d_in[1];
    float* out = (float*)d_out;
    float* acc = (float*)d_ws;

    hipMemsetAsync(d_ws, 0, 16, stream);            // loss accumulator (ws poisoned 0xAA)
    vq_main<<<dim3(1024), dim3(256), 0, stream>>>(z, emb, out, acc);
    vq_finalize<<<dim3(1), dim3(1), 0, stream>>>(acc, out);
}

// Round 4
// 879.779 us; speedup vs baseline: 1.0392x; 1.0392x over previous
//
#include <hip/hip_runtime.h>

// VectorQuantizer: z (8,64,16,64,64) f32, emb (512,64) f32.
// N = 524288, D = 64, K = 512.
// out flat = [ z_q_st (33554432 f32) | loss (1 f32) | indices (524288 f32) ]
//
// Bit-exact replication of the checker's np fp32 arithmetic (verified R3):
//   d[n,k] = fl( fmaf(-2, M_nk, zz_n) + ee_k ),  M_nk = sequential fma chain
//   over c=0..63; zz/ee = numpy pairwise sum-of-squares (n=64 pattern);
//   argmin = strict <, ascending k.
//
// R4 change: kill the LDS pipe bottleneck (R3: 32 broadcast ds_read_b128 per
// 256 fma oversubscribed the single per-CU LDS pipe ~2.5x -> VALUBusy 41%).
// Codebook is now read with BLOCK-UNIFORM indices straight from global memory
// (compiler emits s_load / scalar cache, or at worst 16B broadcast vL1 hits).
// 1 row/thread, 4 codes/iter = 4 independent fma chains, zero LDS.

#define NK       512
#define DD       64
#define LOSS_OFF 33554432
#define IDX_OFF  33554433
#define EE_FOFF  4            // float offset of ee[512] in ws (byte 16)

// numpy pairwise_sum of squares, n=64: 8 strided accumulators combined
// ((r0+r1)+(r2+r3))+((r4+r5)+(r6+r7)); squares rounded separately (asm
// barrier blocks -ffp-contract=fast from fusing square into add).
__device__ __forceinline__ float np_sumsq64(const float* v) {
    float r[8];
    #pragma unroll
    for (int j = 0; j < 8; ++j) {
        float s = v[j] * v[j];
        asm volatile("" : "+v"(s));
        r[j] = s;
    }
    #pragma unroll
    for (int i = 8; i < 64; i += 8) {
        #pragma unroll
        for (int j = 0; j < 8; ++j) {
            float s = v[i + j] * v[i + j];
            asm volatile("" : "+v"(s));
            r[j] += s;
        }
    }
    return ((r[0] + r[1]) + (r[2] + r[3])) + ((r[4] + r[5]) + (r[6] + r[7]));
}

__global__ void vq_ee(const float* __restrict__ emb, float* __restrict__ ws) {
    const int k = blockIdx.x * 256 + threadIdx.x;      // grid 2 x 256
    float row[DD];
    const float* er = emb + k * DD;
    #pragma unroll
    for (int c = 0; c < DD; ++c) row[c] = er[c];
    ws[EE_FOFF + k] = np_sumsq64(row);
}

__global__ __launch_bounds__(256, 4)
void vq_main(const float* __restrict__ z, const float* __restrict__ emb,
             float* __restrict__ out, float* __restrict__ ws) {
    const int n  = blockIdx.x * 256 + threadIdx.x;     // grid 2048 x 256
    const int b  = n >> 16;
    const int sp = n & 65535;
    const float* zp = z + ((size_t)b << 22) + sp;

    float zr[DD];                                      // 64 VGPRs
    #pragma unroll
    for (int c = 0; c < DD; ++c) zr[c] = zp[(size_t)c << 16];
    const float zz = np_sumsq64(zr);

    const float4* __restrict__ e4  = (const float4*)emb;          // 16 f4/row
    const float4* __restrict__ ee4 = (const float4*)(ws + EE_FOFF);

    float best = 3.4e38f;
    int   bi   = 0;

    #pragma unroll 1
    for (int k = 0; k < NK; k += 4) {
        // all indices block-uniform -> scalar-cache (s_load) candidates
        const int r0 = (k + 0) << 4, r1 = (k + 1) << 4;
        const int r2 = (k + 2) << 4, r3 = (k + 3) << 4;
        float m0 = 0.f, m1 = 0.f, m2 = 0.f, m3 = 0.f;  // 4 indep fma chains
        #pragma unroll
        for (int c4 = 0; c4 < 16; ++c4) {
            const float4 e0 = e4[r0 + c4];
            const float4 e1 = e4[r1 + c4];
            const float4 e2 = e4[r2 + c4];
            const float4 e3 = e4[r3 + c4];
            const float z0 = zr[c4 * 4 + 0], z1 = zr[c4 * 4 + 1];
            const float z2 = zr[c4 * 4 + 2], z3 = zr[c4 * 4 + 3];
            m0 = fmaf(z0, e0.x, m0); m0 = fmaf(z1, e0.y, m0);
            m0 = fmaf(z2, e0.z, m0); m0 = fmaf(z3, e0.w, m0);
            m1 = fmaf(z0, e1.x, m1); m1 = fmaf(z1, e1.y, m1);
            m1 = fmaf(z2, e1.z, m1); m1 = fmaf(z3, e1.w, m1);
            m2 = fmaf(z0, e2.x, m2); m2 = fmaf(z1, e2.y, m2);
            m2 = fmaf(z2, e2.z, m2); m2 = fmaf(z3, e2.w, m2);
            m3 = fmaf(z0, e3.x, m3); m3 = fmaf(z1, e3.y, m3);
            m3 = fmaf(z2, e3.z, m3); m3 = fmaf(z3, e3.w, m3);
        }
        const float4 ee = ee4[k >> 2];
        const float d0 = fmaf(-2.f, m0, zz) + ee.x;
        const float d1 = fmaf(-2.f, m1, zz) + ee.y;
        const float d2 = fmaf(-2.f, m2, zz) + ee.z;
        const float d3 = fmaf(-2.f, m3, zz) + ee.w;
        if (d0 < best) { best = d0; bi = k;     }      // strict <, ascending k
        if (d1 < best) { best = d1; bi = k + 1; }
        if (d2 < best) { best = d2; bi = k + 2; }
        if (d3 < best) { best = d3; bi = k + 3; }
    }

    // epilogue: gather z_q row (emb is L1/L2-hot), coalesced writes, loss
    float* op = out + ((size_t)b << 22) + sp;
    const float4* brow = (const float4*)(emb + bi * DD);
    float lsum = 0.f;
    #pragma unroll
    for (int c4 = 0; c4 < 16; ++c4) {
        float4 e = brow[c4];
        float eq[4] = { e.x, e.y, e.z, e.w };
        #pragma unroll
        for (int j = 0; j < 4; ++j) {
            const int c = c4 * 4 + j;
            float d = eq[j] - zr[c];
            lsum = fmaf(d, d, lsum);
            op[(size_t)c << 16] = eq[j];
        }
    }
    out[IDX_OFF + n] = (float)bi;

    #pragma unroll
    for (int off = 32; off > 0; off >>= 1) lsum += __shfl_down(lsum, off);
    if ((threadIdx.x & 63) == 0)
        atomicAdd((double*)ws, (double)lsum);          // fp64: exact final stage
}

__global__ void vq_finalize(const float* __restrict__ ws, float* __restrict__ out) {
    out[LOSS_OFF] = (float)(((const double*)ws)[0] * (1.25 / 33554432.0));
}

extern "C" void kernel_launch(void* const* d_in, const int* in_sizes, int n_in,
                              void* d_out, int out_size, void* d_ws, size_t ws_size,
                              hipStream_t stream) {
    const float* z   = (const float*)d_in[0];
    const float* emb = (const float*)d_in[1];
    float* out = (float*)d_out;
    float* ws  = (float*)d_ws;

    hipMemsetAsync(d_ws, 0, 16, stream);               // zero fp64 loss accumulator
    vq_ee<<<dim3(2), dim3(256), 0, stream>>>(emb, ws);
    vq_main<<<dim3(2048), dim3(256), 0, stream>>>(z, emb, out, ws);
    vq_finalize<<<dim3(1), dim3(1), 0, stream>>>(ws, out);
}

// Round 5
// 756.573 us; speedup vs baseline: 1.2085x; 1.1628x over previous
//
#include <hip/hip_runtime.h>

// VectorQuantizer: z (8,64,16,64,64) f32, emb (512,64) f32.
// N = 524288, D = 64, K = 512.
// out flat = [ z_q_st (33554432 f32) | loss (1 f32) | indices (524288 f32) ]
//
// Bit-exact replication of the checker's np fp32 arithmetic (verified R3):
//   d[n,k] = fl( fmaf(-2, M_nk, zz_n) + ee_k ),  M_nk = sequential fma chain
//   c=0..63; zz/ee = numpy pairwise sum-of-squares (n=64 pattern);
//   argmin = strict <, ascending k.
//
// R5: codebook through the SCALAR pipe. R4's per-lane VMEM e-loads (16 in-
// flight float4 = 64 VGPRs) made the allocator demote zr[] and re-load z from
// global inside the k-loop (VGPR_Count=44 — the tell). Now emb/ee are read
// via address_space(4) pointers (CK's constant-AS trick) -> s_load_dwordx16
// into SGPRs; inner loop is v_fmac v_m, s_e, v_z. VGPRs ~80 -> zr stays
// resident; VALU does (almost) nothing but the 64-fma chains.

#define NK       512
#define DD       64
#define LOSS_OFF 33554432
#define IDX_OFF  33554433
#define EE_FOFF  4            // float offset of ee[512] in ws (byte 16)

typedef float f32x4 __attribute__((ext_vector_type(4)));
#define CONST_AS __attribute__((address_space(4)))

// numpy pairwise_sum of squares, n=64: 8 strided accumulators combined
// ((r0+r1)+(r2+r3))+((r4+r5)+(r6+r7)); squares rounded separately (asm
// barrier blocks -ffp-contract=fast from fusing square into add).
__device__ __forceinline__ float np_sumsq64(const float* v) {
    float r[8];
    #pragma unroll
    for (int j = 0; j < 8; ++j) {
        float s = v[j] * v[j];
        asm volatile("" : "+v"(s));
        r[j] = s;
    }
    #pragma unroll
    for (int i = 8; i < 64; i += 8) {
        #pragma unroll
        for (int j = 0; j < 8; ++j) {
            float s = v[i + j] * v[i + j];
            asm volatile("" : "+v"(s));
            r[j] += s;
        }
    }
    return ((r[0] + r[1]) + (r[2] + r[3])) + ((r[4] + r[5]) + (r[6] + r[7]));
}

__global__ void vq_ee(const float* __restrict__ emb, float* __restrict__ ws) {
    const int k = blockIdx.x * 256 + threadIdx.x;      // grid 2 x 256
    float row[DD];
    const float* er = emb + k * DD;
    #pragma unroll
    for (int c = 0; c < DD; ++c) row[c] = er[c];
    ws[EE_FOFF + k] = np_sumsq64(row);
}

__global__ __launch_bounds__(256, 4)
void vq_main(const float* __restrict__ z, const float* __restrict__ emb,
             float* __restrict__ out, float* __restrict__ ws) {
    const int n  = blockIdx.x * 256 + threadIdx.x;     // grid 2048 x 256
    const int b  = n >> 16;
    const int sp = n & 65535;
    const float* zp = z + ((size_t)b << 22) + sp;

    float zr[DD];                                      // 64 VGPRs, pinned
    #pragma unroll
    for (int c = 0; c < DD; ++c) zr[c] = zp[(size_t)c << 16];
    const float zz = np_sumsq64(zr);
    #pragma unroll
    for (int c = 0; c < DD; ++c) asm volatile("" : "+v"(zr[c]));

    // constant-address-space views -> s_load (scalar cache, SGPR destinations)
    const CONST_AS f32x4* e4  = (const CONST_AS f32x4*)emb;            // 16/row
    const CONST_AS float* eec = (const CONST_AS float*)(ws + EE_FOFF);

    float best = 3.4e38f;
    int   bi   = 0;

    #pragma unroll 1
    for (int k = 0; k < NK; ++k) {
        const CONST_AS f32x4* er = e4 + (k << 4);      // uniform address
        float m = 0.f;                                 // THE sequential chain
        #pragma unroll
        for (int c4 = 0; c4 < 16; ++c4) {
            const f32x4 e = er[c4];                    // s_load_dwordx4/x16
            m = fmaf(zr[c4 * 4 + 0], e.x, m);
            m = fmaf(zr[c4 * 4 + 1], e.y, m);
            m = fmaf(zr[c4 * 4 + 2], e.z, m);
            m = fmaf(zr[c4 * 4 + 3], e.w, m);
        }
        const float d = fmaf(-2.f, m, zz) + eec[k];
        if (d < best) { best = d; bi = k; }            // strict <, ascending k
    }

    // epilogue: gather z_q row (emb L1/L2-hot, divergent bi), coalesced writes
    float* op = out + ((size_t)b << 22) + sp;
    const float4* brow = (const float4*)(emb + bi * DD);
    float lsum = 0.f;
    #pragma unroll
    for (int c4 = 0; c4 < 16; ++c4) {
        float4 e = brow[c4];
        float eq[4] = { e.x, e.y, e.z, e.w };
        #pragma unroll
        for (int j = 0; j < 4; ++j) {
            const int c = c4 * 4 + j;
            float d = eq[j] - zr[c];
            lsum = fmaf(d, d, lsum);
            op[(size_t)c << 16] = eq[j];
        }
    }
    out[IDX_OFF + n] = (float)bi;

    #pragma unroll
    for (int off = 32; off > 0; off >>= 1) lsum += __shfl_down(lsum, off);
    if ((threadIdx.x & 63) == 0)
        atomicAdd((double*)ws, (double)lsum);          // fp64 final accumulation

    asm volatile("" :: "v"(zr[0]));                    // keep pins honest
}

__global__ void vq_finalize(const float* __restrict__ ws, float* __restrict__ out) {
    out[LOSS_OFF] = (float)(((const double*)ws)[0] * (1.25 / 33554432.0));
}

extern "C" void kernel_launch(void* const* d_in, const int* in_sizes, int n_in,
                              void* d_out, int out_size, void* d_ws, size_t ws_size,
                              hipStream_t stream) {
    const float* z   = (const float*)d_in[0];
    const float* emb = (const float*)d_in[1];
    float* out = (float*)d_out;
    float* ws  = (float*)d_ws;

    hipMemsetAsync(d_ws, 0, 16, stream);               // zero fp64 loss accumulator
    vq_ee<<<dim3(2), dim3(256), 0, stream>>>(emb, ws);
    vq_main<<<dim3(2048), dim3(256), 0, stream>>>(z, emb, out, ws);
    vq_finalize<<<dim3(1), dim3(1), 0, stream>>>(ws, out);
}